// Round 1
// baseline (5593.596 us; speedup 1.0000x reference)
//
#include <hip/hip_runtime.h>

#define DD 64
#define ALPHA 0.6f
#define KHOPS 8

__global__ __launch_bounds__(256) void deg_init_kernel(float* deg, int n) {
    int i = blockIdx.x * blockDim.x + threadIdx.x;
    if (i < n) deg[i] = 1.0f;   // self-loop contributes 1
}

__global__ __launch_bounds__(256) void deg_count_kernel(const int* __restrict__ dst,
                                                        float* deg, int e) {
    int i = blockIdx.x * blockDim.x + threadIdx.x;
    if (i < e) atomicAdd(&deg[dst[i]], 1.0f);
}

__global__ __launch_bounds__(256) void dinv_kernel(float* deg, int n) {
    int i = blockIdx.x * blockDim.x + threadIdx.x;
    if (i < n) {
        float d = deg[i];
        deg[i] = (d > 0.0f) ? rsqrtf(d) : 0.0f;   // in-place deg -> dinv
    }
}

// h = ALPHA*x ; bufA = dinv^2 * x  (self-loop term pre-init for hop 1)
__global__ __launch_bounds__(256) void init_kernel(const float4* __restrict__ x,
                                                   const float* __restrict__ dinv,
                                                   float4* __restrict__ h,
                                                   float4* __restrict__ buf, int n4) {
    int i = blockIdx.x * blockDim.x + threadIdx.x;
    if (i >= n4) return;
    int row = i >> 4;                     // 16 float4 per row (D=64)
    float di = dinv[row];
    float w = di * di;
    float4 v = x[i];
    h[i]   = make_float4(ALPHA * v.x, ALPHA * v.y, ALPHA * v.z, ALPHA * v.w);
    buf[i] = make_float4(w * v.x, w * v.y, w * v.z, w * v.w);
}

// 16 threads per edge; each handles one float4 chunk of the 64-wide row.
__global__ __launch_bounds__(256) void scatter_kernel(const int* __restrict__ src,
                                                      const int* __restrict__ dst,
                                                      const float* __restrict__ dinv,
                                                      const float4* __restrict__ xin,
                                                      float* __restrict__ xacc, int e) {
    int t = blockIdx.x * blockDim.x + threadIdx.x;
    int ei = t >> 4;
    if (ei >= e) return;
    int q = t & 15;
    int s = src[ei];
    int d = dst[ei];
    float w = dinv[s] * dinv[d];
    float4 v = xin[(size_t)s * 16 + q];
    float* out = xacc + (size_t)d * 64 + q * 4;
    atomicAdd(out + 0, w * v.x);
    atomicAdd(out + 1, w * v.y);
    atomicAdd(out + 2, w * v.z);
    atomicAdd(out + 3, w * v.w);
}

// h += coef*acc ; optionally next = dinv^2*acc (self-loop pre-init for next hop)
template <int DO_NEXT>
__global__ __launch_bounds__(256) void finish_kernel(float4* __restrict__ h,
                                                     const float4* __restrict__ acc,
                                                     float4* __restrict__ next,
                                                     const float* __restrict__ dinv,
                                                     float coef, int n4) {
    int i = blockIdx.x * blockDim.x + threadIdx.x;
    if (i >= n4) return;
    float4 a = acc[i];
    float4 hv = h[i];
    hv.x += coef * a.x; hv.y += coef * a.y; hv.z += coef * a.z; hv.w += coef * a.w;
    h[i] = hv;
    if (DO_NEXT) {
        int row = i >> 4;
        float di = dinv[row];
        float w = di * di;
        next[i] = make_float4(w * a.x, w * a.y, w * a.z, w * a.w);
    }
}

// out[i][j] = (relu?) sum_d in[i][d] * w[j][d] + b[j]
// 256 threads, 32 rows per block, w staged transposed in LDS (stride 65: conflict-free).
__global__ __launch_bounds__(256) void gemm_kernel(const float* __restrict__ in,
                                                   const float* __restrict__ w,
                                                   const float* __restrict__ b,
                                                   float* __restrict__ out,
                                                   int n, int relu) {
    __shared__ float ws[64 * 65];
    __shared__ float ins[32 * 64];
    int t = threadIdx.x;

    // load w transposed: ws[d*65 + j] = w[j*64 + d]
    #pragma unroll
    for (int k = 0; k < 16; ++k) {
        int idx = t + k * 256;
        int j = idx >> 6, d = idx & 63;
        ws[d * 65 + j] = w[idx];
    }

    int row0 = blockIdx.x * 32;
    const float4* in4 = (const float4*)in;
    #pragma unroll
    for (int k = 0; k < 2; ++k) {
        int idx = t + k * 256;            // 512 float4 = 32 rows
        int r = idx >> 4;
        int gr = row0 + r;
        float4 v = (gr < n) ? in4[(size_t)gr * 16 + (idx & 15)]
                            : make_float4(0.f, 0.f, 0.f, 0.f);
        ((float4*)ins)[idx] = v;
    }
    __syncthreads();

    int col = t & 63;
    int rgrp = t >> 6;                    // 0..3, each handles 8 rows
    float acc[8] = {0.f, 0.f, 0.f, 0.f, 0.f, 0.f, 0.f, 0.f};
    #pragma unroll 8
    for (int d = 0; d < 64; ++d) {
        float wv = ws[d * 65 + col];
        #pragma unroll
        for (int r = 0; r < 8; ++r)
            acc[r] += ins[(rgrp * 8 + r) * 64 + d] * wv;
    }
    float bv = b[col];
    #pragma unroll
    for (int r = 0; r < 8; ++r) {
        int gr = row0 + rgrp * 8 + r;
        if (gr < n) {
            float v = acc[r] + bv;
            if (relu) v = fmaxf(v, 0.0f);
            out[(size_t)gr * 64 + col] = v;
        }
    }
}

extern "C" void kernel_launch(void* const* d_in, const int* in_sizes, int n_in,
                              void* d_out, int out_size, void* d_ws, size_t ws_size,
                              hipStream_t stream) {
    const float* x      = (const float*)d_in[0];
    const float* w_conv = (const float*)d_in[1];
    const float* b_conv = (const float*)d_in[2];
    const float* w1     = (const float*)d_in[3];
    const float* b1     = (const float*)d_in[4];
    const float* w2     = (const float*)d_in[5];
    const float* b2     = (const float*)d_in[6];
    const int*   ei     = (const int*)d_in[7];

    int n = in_sizes[0] / DD;       // 50000
    int e = in_sizes[7] / 2;        // 800000
    const int* src = ei;
    const int* dst = ei + e;

    float* ws   = (float*)d_ws;
    float* dinv = ws;                                    // n floats
    float* bufA = ws + 65536;                            // n*64
    float* bufB = bufA + (size_t)n * DD;                 // n*64
    float* h    = bufB + (size_t)n * DD;                 // n*64
    float* out  = (float*)d_out;

    const int B = 256;
    int n4 = n * (DD / 4);          // float4 count per feature buffer

    deg_init_kernel<<<(n + B - 1) / B, B, 0, stream>>>(dinv, n);
    deg_count_kernel<<<(e + B - 1) / B, B, 0, stream>>>(dst, dinv, e);
    dinv_kernel<<<(n + B - 1) / B, B, 0, stream>>>(dinv, n);

    init_kernel<<<(n4 + B - 1) / B, B, 0, stream>>>(
        (const float4*)x, dinv, (float4*)h, (float4*)bufA, n4);

    float coef = (1.0f - ALPHA) / (float)KHOPS;

    const float* gather = x;       // gather source for current hop
    float* accb = bufA;            // scatter target (pre-initialized with self-loop)
    float* nextb = bufB;           // will hold self-loop pre-init for next hop
    int sblocks = ((e * 16) + B - 1) / B;
    int fblocks = (n4 + B - 1) / B;

    for (int k = 0; k < KHOPS; ++k) {
        scatter_kernel<<<sblocks, B, 0, stream>>>(src, dst, dinv,
                                                  (const float4*)gather, accb, e);
        if (k < KHOPS - 1) {
            finish_kernel<1><<<fblocks, B, 0, stream>>>(
                (float4*)h, (const float4*)accb, (float4*)nextb, dinv, coef, n4);
        } else {
            finish_kernel<0><<<fblocks, B, 0, stream>>>(
                (float4*)h, (const float4*)accb, nullptr, dinv, coef, n4);
        }
        gather = accb;
        float* tmp = accb; accb = nextb; nextb = tmp;
    }

    // dense head: relu(h@w_conv^T+b) -> relu(@w1^T+b1) -> @w2^T+b2
    int gblocks = (n + 31) / 32;
    gemm_kernel<<<gblocks, B, 0, stream>>>(h, w_conv, b_conv, bufA, n, 1);
    gemm_kernel<<<gblocks, B, 0, stream>>>(bufA, w1, b1, bufB, n, 1);
    gemm_kernel<<<gblocks, B, 0, stream>>>(bufB, w2, b2, out, n, 0);
}

// Round 2
// 686.624 us; speedup vs baseline: 8.1465x; 8.1465x over previous
//
#include <hip/hip_runtime.h>

#define DD 64
#define ALPHA 0.6f
#define KHOPS 8

// cnt[d]++ over edges (int atomics, cheap)
__global__ __launch_bounds__(256) void deg_count_kernel(const int* __restrict__ dst,
                                                        int* __restrict__ cnt, int e) {
    int i = blockIdx.x * blockDim.x + threadIdx.x;
    if (i < e) atomicAdd(&cnt[dst[i]], 1);
}

// dinv[i] = rsqrt(cnt[i] + 1)   (+1 = self loop)
__global__ __launch_bounds__(256) void dinv_kernel(const int* __restrict__ cnt,
                                                   float* __restrict__ dinv, int n) {
    int i = blockIdx.x * blockDim.x + threadIdx.x;
    if (i < n) dinv[i] = rsqrtf((float)(cnt[i] + 1));
}

// single-block exclusive scan of cnt -> rowptr, cursor (cursor may alias cnt)
__global__ __launch_bounds__(1024) void scan_kernel(const int* __restrict__ cnt,
                                                    int* __restrict__ rowptr,
                                                    int* __restrict__ cursor, int n) {
    __shared__ int sums[1024];
    int t = threadIdx.x;
    int chunk = (n + 1023) >> 10;
    int s0 = t * chunk;
    int s1 = min(n, s0 + chunk);
    int sum = 0;
    for (int i = s0; i < s1; ++i) sum += cnt[i];
    sums[t] = sum;
    __syncthreads();
    for (int off = 1; off < 1024; off <<= 1) {
        int tmp = (t >= off) ? sums[t - off] : 0;
        __syncthreads();
        sums[t] += tmp;
        __syncthreads();
    }
    int run = sums[t] - sum;   // exclusive prefix at chunk start
    for (int i = s0; i < s1; ++i) {
        int c = cnt[i];        // read BEFORE write (cursor may alias cnt)
        rowptr[i] = run;
        cursor[i] = run;
        run += c;
    }
    if (t == 1023) rowptr[n] = run;
}

// ecsr[pos] = {src, w = dinv[s]*dinv[d]} bucketed by dst
__global__ __launch_bounds__(256) void fill_kernel(const int* __restrict__ src,
                                                   const int* __restrict__ dst,
                                                   const float* __restrict__ dinv,
                                                   int* __restrict__ cursor,
                                                   int2* __restrict__ ecsr, int e) {
    int i = blockIdx.x * blockDim.x + threadIdx.x;
    if (i >= e) return;
    int s = src[i], d = dst[i];
    int pos = atomicAdd(&cursor[d], 1);
    float w = dinv[s] * dinv[d];
    ecsr[pos] = make_int2(s, __float_as_int(w));
}

// h = ALPHA * x
__global__ __launch_bounds__(256) void init_kernel(const float4* __restrict__ x,
                                                   float4* __restrict__ h, int n4) {
    int i = blockIdx.x * blockDim.x + threadIdx.x;
    if (i >= n4) return;
    float4 v = x[i];
    h[i] = make_float4(ALPHA * v.x, ALPHA * v.y, ALPHA * v.z, ALPHA * v.w);
}

// One wave (64 lanes) per node; lane f owns feature column f.
// xout[d] = dinv[d]^2*xin[d] + sum_e w_e * xin[src_e] ;  h[d] += coef*xout[d]
__global__ __launch_bounds__(256) void hop_kernel(const int* __restrict__ rowptr,
                                                  const int2* __restrict__ ecsr,
                                                  const float* __restrict__ dinv,
                                                  const float* __restrict__ xin,
                                                  float* __restrict__ xout,
                                                  float* __restrict__ h,
                                                  float coef, int n) {
    int t = blockIdx.x * blockDim.x + threadIdx.x;
    int node = t >> 6;
    if (node >= n) return;
    int f = t & 63;
    float di = dinv[node];
    size_t idx = (size_t)node * 64 + f;
    float acc = di * di * xin[idx];          // self loop
    int e0 = rowptr[node], e1 = rowptr[node + 1];
    int e = e0;
    for (; e + 1 < e1; e += 2) {             // unroll x2: two gathers in flight
        int2 ea = ecsr[e];
        int2 eb = ecsr[e + 1];
        float xa = xin[(size_t)ea.x * 64 + f];
        float xb = xin[(size_t)eb.x * 64 + f];
        acc += __int_as_float(ea.y) * xa;
        acc += __int_as_float(eb.y) * xb;
    }
    if (e < e1) {
        int2 ea = ecsr[e];
        acc += __int_as_float(ea.y) * xin[(size_t)ea.x * 64 + f];
    }
    xout[idx] = acc;
    h[idx] += coef * acc;
}

// out[i][j] = (relu?) sum_d in[i][d] * w[j][d] + b[j]
__global__ __launch_bounds__(256) void gemm_kernel(const float* __restrict__ in,
                                                   const float* __restrict__ w,
                                                   const float* __restrict__ b,
                                                   float* __restrict__ out,
                                                   int n, int relu) {
    __shared__ float ws[64 * 65];
    __shared__ float ins[32 * 64];
    int t = threadIdx.x;

    #pragma unroll
    for (int k = 0; k < 16; ++k) {
        int idx = t + k * 256;
        int j = idx >> 6, d = idx & 63;
        ws[d * 65 + j] = w[idx];
    }

    int row0 = blockIdx.x * 32;
    const float4* in4 = (const float4*)in;
    #pragma unroll
    for (int k = 0; k < 2; ++k) {
        int idx = t + k * 256;
        int r = idx >> 4;
        int gr = row0 + r;
        float4 v = (gr < n) ? in4[(size_t)gr * 16 + (idx & 15)]
                            : make_float4(0.f, 0.f, 0.f, 0.f);
        ((float4*)ins)[idx] = v;
    }
    __syncthreads();

    int col = t & 63;
    int rgrp = t >> 6;
    float acc[8] = {0.f, 0.f, 0.f, 0.f, 0.f, 0.f, 0.f, 0.f};
    #pragma unroll 8
    for (int d = 0; d < 64; ++d) {
        float wv = ws[d * 65 + col];
        #pragma unroll
        for (int r = 0; r < 8; ++r)
            acc[r] += ins[(rgrp * 8 + r) * 64 + d] * wv;
    }
    float bv = b[col];
    #pragma unroll
    for (int r = 0; r < 8; ++r) {
        int gr = row0 + rgrp * 8 + r;
        if (gr < n) {
            float v = acc[r] + bv;
            if (relu) v = fmaxf(v, 0.0f);
            out[(size_t)gr * 64 + col] = v;
        }
    }
}

extern "C" void kernel_launch(void* const* d_in, const int* in_sizes, int n_in,
                              void* d_out, int out_size, void* d_ws, size_t ws_size,
                              hipStream_t stream) {
    const float* x      = (const float*)d_in[0];
    const float* w_conv = (const float*)d_in[1];
    const float* b_conv = (const float*)d_in[2];
    const float* w1     = (const float*)d_in[3];
    const float* b1     = (const float*)d_in[4];
    const float* w2     = (const float*)d_in[5];
    const float* b2     = (const float*)d_in[6];
    const int*   ei     = (const int*)d_in[7];

    int n = in_sizes[0] / DD;       // 50000
    int e = in_sizes[7] / 2;        // 800000
    const int* src = ei;
    const int* dst = ei + e;

    // workspace layout (bytes): cnt/cursor | dinv | rowptr | ecsr | bufA | bufB
    char* wsb = (char*)d_ws;
    int*   cnt    = (int*)wsb;                          // n ints (reused as cursor)
    float* dinv   = (float*)(wsb + 65536 * 4);          // n floats
    int*   rowptr = (int*)(wsb + 2 * 65536 * 4);        // n+1 ints
    int2*  ecsr   = (int2*)(wsb + 3 * 65536 * 4);       // e int2
    float* bufA   = (float*)(wsb + 3 * 65536 * 4 + (size_t)e * 8);
    float* bufB   = bufA + (size_t)n * DD;
    float* h      = (float*)d_out;                      // d_out doubles as h scratch

    const int B = 256;
    int n4 = n * (DD / 4);

    hipMemsetAsync(cnt, 0, (size_t)n * sizeof(int), stream);
    deg_count_kernel<<<(e + B - 1) / B, B, 0, stream>>>(dst, cnt, e);
    dinv_kernel<<<(n + B - 1) / B, B, 0, stream>>>(cnt, dinv, n);
    scan_kernel<<<1, 1024, 0, stream>>>(cnt, rowptr, cnt /*cursor aliases cnt*/, n);
    fill_kernel<<<(e + B - 1) / B, B, 0, stream>>>(src, dst, dinv, cnt, ecsr, e);

    init_kernel<<<(n4 + B - 1) / B, B, 0, stream>>>((const float4*)x, (float4*)h, n4);

    float coef = (1.0f - ALPHA) / (float)KHOPS;
    int hblocks = ((n * 64) + B - 1) / B;

    const float* gather = x;
    float* outb = bufA;
    float* altb = bufB;
    for (int k = 0; k < KHOPS; ++k) {
        hop_kernel<<<hblocks, B, 0, stream>>>(rowptr, ecsr, dinv, gather, outb, h,
                                              coef, n);
        gather = outb;
        float* tmp = outb; outb = altb; altb = tmp;
    }

    int gblocks = (n + 31) / 32;
    gemm_kernel<<<gblocks, B, 0, stream>>>(h, w_conv, b_conv, bufA, n, 1);
    gemm_kernel<<<gblocks, B, 0, stream>>>(bufA, w1, b1, bufB, n, 1);
    gemm_kernel<<<gblocks, B, 0, stream>>>(bufB, w2, b2, (float*)d_out, n, 0);
}

// Round 3
// 439.136 us; speedup vs baseline: 12.7377x; 1.5636x over previous
//
#include <hip/hip_runtime.h>

#define DD 64
#define ALPHA 0.6f
#define KHOPS 8

static __device__ __forceinline__ unsigned short f2bf(float f) {
    unsigned int u = __float_as_uint(f);
    unsigned int r = (u + 0x7FFFu + ((u >> 16) & 1u)) >> 16;   // RTN-even
    return (unsigned short)r;
}
static __device__ __forceinline__ float bf2f(unsigned short h) {
    return __uint_as_float(((unsigned int)h) << 16);
}

__global__ __launch_bounds__(256) void deg_count_kernel(const int* __restrict__ dst,
                                                        int* __restrict__ cnt, int e) {
    int i = blockIdx.x * blockDim.x + threadIdx.x;
    if (i < e) atomicAdd(&cnt[dst[i]], 1);
}

__global__ __launch_bounds__(256) void dinv_kernel(const int* __restrict__ cnt,
                                                   float* __restrict__ dinv, int n) {
    int i = blockIdx.x * blockDim.x + threadIdx.x;
    if (i < n) dinv[i] = rsqrtf((float)(cnt[i] + 1));
}

// ---- hierarchical exclusive scan of cnt -> rowptr, cursor ----
__global__ __launch_bounds__(256) void scan1_kernel(const int* __restrict__ cnt,
                                                    int* __restrict__ partials, int n) {
    int i = blockIdx.x * 256 + threadIdx.x;
    int v = (i < n) ? cnt[i] : 0;
    #pragma unroll
    for (int off = 1; off < 64; off <<= 1) v += __shfl_down(v, off, 64);
    __shared__ int ws[4];
    if ((threadIdx.x & 63) == 0) ws[threadIdx.x >> 6] = v;
    __syncthreads();
    if (threadIdx.x == 0) partials[blockIdx.x] = ws[0] + ws[1] + ws[2] + ws[3];
}

__global__ __launch_bounds__(1024) void scan2_kernel(int* __restrict__ partials, int nb) {
    __shared__ int s[1024];
    int t = threadIdx.x;
    int v = (t < nb) ? partials[t] : 0;
    s[t] = v;
    __syncthreads();
    for (int off = 1; off < 1024; off <<= 1) {
        int tmp = (t >= off) ? s[t - off] : 0;
        __syncthreads();
        s[t] += tmp;
        __syncthreads();
    }
    if (t < nb) partials[t] = s[t] - v;   // exclusive
}

__global__ __launch_bounds__(256) void scan3_kernel(const int* __restrict__ cnt,
                                                    const int* __restrict__ partials,
                                                    int* __restrict__ rowptr,
                                                    int* __restrict__ cursor, int n) {
    int t = threadIdx.x;
    int i = blockIdx.x * 256 + t;
    int v = (i < n) ? cnt[i] : 0;
    int lane = t & 63;
    int incl = v;
    #pragma unroll
    for (int off = 1; off < 64; off <<= 1) {
        int u = __shfl_up(incl, off, 64);
        if (lane >= off) incl += u;
    }
    __shared__ int wsum[4];
    if (lane == 63) wsum[t >> 6] = incl;
    __syncthreads();
    int woff = 0;
    for (int w = 0; w < (t >> 6); ++w) woff += wsum[w];
    int excl = incl - v + woff + partials[blockIdx.x];
    if (i < n) { rowptr[i] = excl; cursor[i] = excl; }
    if (i == n - 1) rowptr[n] = excl + v;
}

__global__ __launch_bounds__(256) void fill_kernel(const int* __restrict__ src,
                                                   const int* __restrict__ dst,
                                                   const float* __restrict__ dinv,
                                                   int* __restrict__ cursor,
                                                   int2* __restrict__ ecsr, int e) {
    int i = blockIdx.x * blockDim.x + threadIdx.x;
    if (i >= e) return;
    int s = src[i], d = dst[i];
    int pos = atomicAdd(&cursor[d], 1);
    float w = dinv[s] * dinv[d];
    ecsr[pos] = make_int2(s, __float_as_int(w));
}

// h = ALPHA*x (f32) ; xb = bf16(x)
__global__ __launch_bounds__(256) void init_kernel(const float4* __restrict__ x,
                                                   float4* __restrict__ h,
                                                   ushort4* __restrict__ xb, int n4) {
    int i = blockIdx.x * blockDim.x + threadIdx.x;
    if (i >= n4) return;
    float4 v = x[i];
    h[i] = make_float4(ALPHA * v.x, ALPHA * v.y, ALPHA * v.z, ALPHA * v.w);
    ushort4 b;
    b.x = f2bf(v.x); b.y = f2bf(v.y); b.z = f2bf(v.z); b.w = f2bf(v.w);
    xb[i] = b;
}

// One wave per node, lane = feature. bf16 gather, f32 accumulate.
// DO_H: h += coef*(x_{k-1} + x_k)  (paired update on even hops)
template <int DO_H>
__global__ __launch_bounds__(256) void hop_kernel(const int* __restrict__ rowptr,
                                                  const int2* __restrict__ ecsr,
                                                  const float* __restrict__ dinv,
                                                  const unsigned short* __restrict__ xin,
                                                  unsigned short* __restrict__ xout,
                                                  float* __restrict__ h,
                                                  float coef, int n) {
    int t = blockIdx.x * blockDim.x + threadIdx.x;
    int node = t >> 6;
    if (node >= n) return;
    int f = t & 63;
    size_t idx = (size_t)node * 64 + f;
    float xprev = bf2f(xin[idx]);
    float di = dinv[node];
    float acc = di * di * xprev;               // self loop
    int e0 = rowptr[node], e1 = rowptr[node + 1];
    int e = e0;
    for (; e + 3 < e1; e += 4) {
        int2 a = ecsr[e], b = ecsr[e + 1], c = ecsr[e + 2], d = ecsr[e + 3];
        float xa = bf2f(xin[(size_t)a.x * 64 + f]);
        float xb = bf2f(xin[(size_t)b.x * 64 + f]);
        float xc = bf2f(xin[(size_t)c.x * 64 + f]);
        float xd = bf2f(xin[(size_t)d.x * 64 + f]);
        acc += __int_as_float(a.y) * xa;
        acc += __int_as_float(b.y) * xb;
        acc += __int_as_float(c.y) * xc;
        acc += __int_as_float(d.y) * xd;
    }
    for (; e < e1; ++e) {
        int2 a = ecsr[e];
        acc += __int_as_float(a.y) * bf2f(xin[(size_t)a.x * 64 + f]);
    }
    xout[idx] = f2bf(acc);
    if (DO_H) h[idx] += coef * (xprev + acc);
}

// fused 3-layer MLP: out = relu(relu(h Wc^T+bc) W1^T+b1) W2^T+b2
__global__ __launch_bounds__(256) void mlp_kernel(const float* __restrict__ h,
                                                  const float* __restrict__ wc,
                                                  const float* __restrict__ bc,
                                                  const float* __restrict__ w1,
                                                  const float* __restrict__ b1,
                                                  const float* __restrict__ w2,
                                                  const float* __restrict__ b2,
                                                  float* __restrict__ out, int n) {
    __shared__ float ws[3][64 * 65];
    __shared__ float buf[32 * 64];
    int t = threadIdx.x;

    const float* wmats[3] = {wc, w1, w2};
    #pragma unroll
    for (int m = 0; m < 3; ++m) {
        const float* w = wmats[m];
        #pragma unroll
        for (int k = 0; k < 16; ++k) {
            int idx = t + k * 256;
            int j = idx >> 6, d = idx & 63;
            ws[m][d * 65 + j] = w[idx];
        }
    }

    int row0 = blockIdx.x * 32;
    const float4* in4 = (const float4*)h;
    #pragma unroll
    for (int k = 0; k < 2; ++k) {
        int idx = t + k * 256;
        int r = idx >> 4;
        int gr = row0 + r;
        float4 v = (gr < n) ? in4[(size_t)gr * 16 + (idx & 15)]
                            : make_float4(0.f, 0.f, 0.f, 0.f);
        ((float4*)buf)[idx] = v;
    }
    __syncthreads();

    int col = t & 63;
    int rg = t >> 6;
    const float* biases[3] = {bc, b1, b2};
    float so[8];
    #pragma unroll
    for (int m = 0; m < 3; ++m) {
        float acc[8] = {0.f, 0.f, 0.f, 0.f, 0.f, 0.f, 0.f, 0.f};
        #pragma unroll 8
        for (int d = 0; d < 64; ++d) {
            float wv = ws[m][d * 65 + col];
            #pragma unroll
            for (int r = 0; r < 8; ++r)
                acc[r] += buf[(rg * 8 + r) * 64 + d] * wv;
        }
        float bv = biases[m][col];
        #pragma unroll
        for (int r = 0; r < 8; ++r) {
            float v = acc[r] + bv;
            so[r] = (m < 2) ? fmaxf(v, 0.0f) : v;
        }
        __syncthreads();
        if (m < 2) {
            #pragma unroll
            for (int r = 0; r < 8; ++r) buf[(rg * 8 + r) * 64 + col] = so[r];
            __syncthreads();
        }
    }
    #pragma unroll
    for (int r = 0; r < 8; ++r) {
        int gr = row0 + rg * 8 + r;
        if (gr < n) out[(size_t)gr * 64 + col] = so[r];
    }
}

extern "C" void kernel_launch(void* const* d_in, const int* in_sizes, int n_in,
                              void* d_out, int out_size, void* d_ws, size_t ws_size,
                              hipStream_t stream) {
    const float* x      = (const float*)d_in[0];
    const float* w_conv = (const float*)d_in[1];
    const float* b_conv = (const float*)d_in[2];
    const float* w1     = (const float*)d_in[3];
    const float* b1     = (const float*)d_in[4];
    const float* w2     = (const float*)d_in[5];
    const float* b2     = (const float*)d_in[6];
    const int*   ei     = (const int*)d_in[7];

    int n = in_sizes[0] / DD;       // 50000
    int e = in_sizes[7] / 2;        // 800000
    const int* src = ei;
    const int* dst = ei + e;

    // workspace layout
    char* wsb = (char*)d_ws;
    const size_t SLOT = 256 * 1024;
    int*   cnt      = (int*)(wsb + 0 * SLOT);
    float* dinv     = (float*)(wsb + 1 * SLOT);
    int*   rowptr   = (int*)(wsb + 2 * SLOT);
    int*   cursor   = (int*)(wsb + 3 * SLOT);
    int*   partials = (int*)(wsb + 4 * SLOT);
    int2*  ecsr     = (int2*)(wsb + 5 * SLOT);                    // e*8 = 6.4 MB
    unsigned short* xb0 = (unsigned short*)(wsb + 5 * SLOT + (size_t)e * 8);
    unsigned short* xb1 = xb0 + (size_t)n * DD;                   // 6.4 MB each
    float* h = (float*)d_out;

    const int B = 256;
    int n4 = n * (DD / 4);
    int nb = (n + 255) / 256;

    hipMemsetAsync(cnt, 0, (size_t)n * sizeof(int), stream);
    deg_count_kernel<<<(e + B - 1) / B, B, 0, stream>>>(dst, cnt, e);
    dinv_kernel<<<(n + B - 1) / B, B, 0, stream>>>(cnt, dinv, n);
    scan1_kernel<<<nb, B, 0, stream>>>(cnt, partials, n);
    scan2_kernel<<<1, 1024, 0, stream>>>(partials, nb);
    scan3_kernel<<<nb, B, 0, stream>>>(cnt, partials, rowptr, cursor, n);
    fill_kernel<<<(e + B - 1) / B, B, 0, stream>>>(src, dst, dinv, cursor, ecsr, e);

    init_kernel<<<(n4 + B - 1) / B, B, 0, stream>>>(
        (const float4*)x, (float4*)h, (ushort4*)xb0, n4);

    float coef = (1.0f - ALPHA) / (float)KHOPS;
    int hblocks = ((n * 64) + B - 1) / B;

    unsigned short* cur = xb0;
    unsigned short* nxt = xb1;
    for (int k = 1; k <= KHOPS; ++k) {
        if (k % 2 == 0)
            hop_kernel<1><<<hblocks, B, 0, stream>>>(rowptr, ecsr, dinv, cur, nxt, h,
                                                     coef, n);
        else
            hop_kernel<0><<<hblocks, B, 0, stream>>>(rowptr, ecsr, dinv, cur, nxt, h,
                                                     coef, n);
        unsigned short* tmp = cur; cur = nxt; nxt = tmp;
    }

    mlp_kernel<<<(n + 31) / 32, B, 0, stream>>>(h, w_conv, b_conv, w1, b1, w2, b2,
                                                (float*)d_out, n);
}

// Round 4
// 401.801 us; speedup vs baseline: 13.9213x; 1.0929x over previous
//
#include <hip/hip_runtime.h>

#define DD 64
#define ALPHA 0.6f
#define KHOPS 8

static __device__ __forceinline__ unsigned short f2bf(float f) {
    unsigned int u = __float_as_uint(f);
    unsigned int r = (u + 0x7FFFu + ((u >> 16) & 1u)) >> 16;   // RTN-even
    return (unsigned short)r;
}
static __device__ __forceinline__ float bf2f(unsigned short h) {
    return __uint_as_float(((unsigned int)h) << 16);
}
static __device__ __forceinline__ unsigned int pack2bf(float lo, float hi) {
    return (unsigned int)f2bf(lo) | ((unsigned int)f2bf(hi) << 16);
}

__global__ __launch_bounds__(256) void deg_count_kernel(const int* __restrict__ dst,
                                                        int* __restrict__ cnt, int e) {
    int i = blockIdx.x * blockDim.x + threadIdx.x;
    if (i < e) atomicAdd(&cnt[dst[i]], 1);
}

__global__ __launch_bounds__(256) void dinv_kernel(const int* __restrict__ cnt,
                                                   float* __restrict__ dinv, int n) {
    int i = blockIdx.x * blockDim.x + threadIdx.x;
    if (i < n) dinv[i] = rsqrtf((float)(cnt[i] + 1));
}

// ---- hierarchical exclusive scan of cnt -> rowptr, cursor ----
__global__ __launch_bounds__(256) void scan1_kernel(const int* __restrict__ cnt,
                                                    int* __restrict__ partials, int n) {
    int i = blockIdx.x * 256 + threadIdx.x;
    int v = (i < n) ? cnt[i] : 0;
    #pragma unroll
    for (int off = 1; off < 64; off <<= 1) v += __shfl_down(v, off, 64);
    __shared__ int ws[4];
    if ((threadIdx.x & 63) == 0) ws[threadIdx.x >> 6] = v;
    __syncthreads();
    if (threadIdx.x == 0) partials[blockIdx.x] = ws[0] + ws[1] + ws[2] + ws[3];
}

__global__ __launch_bounds__(1024) void scan2_kernel(int* __restrict__ partials, int nb) {
    __shared__ int s[1024];
    int t = threadIdx.x;
    int v = (t < nb) ? partials[t] : 0;
    s[t] = v;
    __syncthreads();
    for (int off = 1; off < 1024; off <<= 1) {
        int tmp = (t >= off) ? s[t - off] : 0;
        __syncthreads();
        s[t] += tmp;
        __syncthreads();
    }
    if (t < nb) partials[t] = s[t] - v;   // exclusive
}

__global__ __launch_bounds__(256) void scan3_kernel(const int* __restrict__ cnt,
                                                    const int* __restrict__ partials,
                                                    int* __restrict__ rowptr,
                                                    int* __restrict__ cursor, int n) {
    int t = threadIdx.x;
    int i = blockIdx.x * 256 + t;
    int v = (i < n) ? cnt[i] : 0;
    int lane = t & 63;
    int incl = v;
    #pragma unroll
    for (int off = 1; off < 64; off <<= 1) {
        int u = __shfl_up(incl, off, 64);
        if (lane >= off) incl += u;
    }
    __shared__ int wsum[4];
    if (lane == 63) wsum[t >> 6] = incl;
    __syncthreads();
    int woff = 0;
    for (int w = 0; w < (t >> 6); ++w) woff += wsum[w];
    int excl = incl - v + woff + partials[blockIdx.x];
    if (i < n) { rowptr[i] = excl; cursor[i] = excl; }
    if (i == n - 1) rowptr[n] = excl + v;
}

__global__ __launch_bounds__(256) void fill_kernel(const int* __restrict__ src,
                                                   const int* __restrict__ dst,
                                                   const float* __restrict__ dinv,
                                                   int* __restrict__ cursor,
                                                   int2* __restrict__ ecsr, int e) {
    int i = blockIdx.x * blockDim.x + threadIdx.x;
    if (i >= e) return;
    int s = src[i], d = dst[i];
    int pos = atomicAdd(&cursor[d], 1);
    float w = dinv[s] * dinv[d];
    ecsr[pos] = make_int2(s, __float_as_int(w));
}

// h = ALPHA*x (f32) ; xb = bf16(x)
__global__ __launch_bounds__(256) void init_kernel(const float4* __restrict__ x,
                                                   float4* __restrict__ h,
                                                   ushort4* __restrict__ xb, int n4) {
    int i = blockIdx.x * blockDim.x + threadIdx.x;
    if (i >= n4) return;
    float4 v = x[i];
    h[i] = make_float4(ALPHA * v.x, ALPHA * v.y, ALPHA * v.z, ALPHA * v.w);
    ushort4 b;
    b.x = f2bf(v.x); b.y = f2bf(v.y); b.z = f2bf(v.z); b.w = f2bf(v.w);
    xb[i] = b;
}

static __device__ __forceinline__ void fma8(float* acc, uint4 v, float w) {
    acc[0] += w * __uint_as_float(v.x << 16);
    acc[1] += w * __uint_as_float(v.x & 0xffff0000u);
    acc[2] += w * __uint_as_float(v.y << 16);
    acc[3] += w * __uint_as_float(v.y & 0xffff0000u);
    acc[4] += w * __uint_as_float(v.z << 16);
    acc[5] += w * __uint_as_float(v.z & 0xffff0000u);
    acc[6] += w * __uint_as_float(v.w << 16);
    acc[7] += w * __uint_as_float(v.w & 0xffff0000u);
}

// One wave per node. lane = (group g = lane>>3) x (slice s = lane&7).
// Group g processes edges e0+i*8+g; each lane gathers a 16B row slice (8 bf16).
// => each gather instruction has 8 independent rows in flight.
// 3-step shfl_xor butterfly folds the 8 group partials; group 0 writes.
template <int DO_H>
__global__ __launch_bounds__(256) void hop_kernel(const int* __restrict__ rowptr,
                                                  const int2* __restrict__ ecsr,
                                                  const float* __restrict__ dinv,
                                                  const unsigned short* __restrict__ xin,
                                                  unsigned short* __restrict__ xout,
                                                  float* __restrict__ h,
                                                  float coef, int n) {
    int wid = (blockIdx.x * blockDim.x + threadIdx.x) >> 6;   // wave id = node
    if (wid >= n) return;
    int lane = threadIdx.x & 63;
    int g = lane >> 3;
    int s = lane & 7;
    int node = wid;

    int e0 = rowptr[node];
    int e1 = rowptr[node + 1];

    float acc[8] = {0.f, 0.f, 0.f, 0.f, 0.f, 0.f, 0.f, 0.f};
    float xprev[8];

    // self loop on group 0 (also captures xprev slice for the h update)
    if (g == 0) {
        float di = dinv[node];
        float w = di * di;
        uint4 v = *(const uint4*)(xin + (size_t)node * 64 + s * 8);
        xprev[0] = __uint_as_float(v.x << 16);
        xprev[1] = __uint_as_float(v.x & 0xffff0000u);
        xprev[2] = __uint_as_float(v.y << 16);
        xprev[3] = __uint_as_float(v.y & 0xffff0000u);
        xprev[4] = __uint_as_float(v.z << 16);
        xprev[5] = __uint_as_float(v.z & 0xffff0000u);
        xprev[6] = __uint_as_float(v.w << 16);
        xprev[7] = __uint_as_float(v.w & 0xffff0000u);
        #pragma unroll
        for (int j = 0; j < 8; ++j) acc[j] = w * xprev[j];
    }

    int deg = e1 - e0;
    int niter = (deg + 7) >> 3;
    for (int i = 0; i < niter; ++i) {
        int eidx = e0 + (i << 3) + g;
        bool valid = eidx < e1;
        int ce = valid ? eidx : (e1 - 1);
        int2 ed = ecsr[ce];
        float w = valid ? __int_as_float(ed.y) : 0.0f;
        uint4 v = *(const uint4*)(xin + (size_t)ed.x * 64 + s * 8);
        fma8(acc, v, w);
    }

    // fold the 8 group partials (butterfly over the g bits; s preserved)
    #pragma unroll
    for (int off = 8; off < 64; off <<= 1) {
        #pragma unroll
        for (int j = 0; j < 8; ++j) acc[j] += __shfl_xor(acc[j], off, 64);
    }

    if (g == 0) {
        uint4 o;
        o.x = pack2bf(acc[0], acc[1]);
        o.y = pack2bf(acc[2], acc[3]);
        o.z = pack2bf(acc[4], acc[5]);
        o.w = pack2bf(acc[6], acc[7]);
        *(uint4*)(xout + (size_t)node * 64 + s * 8) = o;
        if (DO_H) {
            float* hp = h + (size_t)node * 64 + s * 8;
            float4 h0 = *(float4*)hp;
            float4 h1 = *(float4*)(hp + 4);
            h0.x += coef * (xprev[0] + acc[0]);
            h0.y += coef * (xprev[1] + acc[1]);
            h0.z += coef * (xprev[2] + acc[2]);
            h0.w += coef * (xprev[3] + acc[3]);
            h1.x += coef * (xprev[4] + acc[4]);
            h1.y += coef * (xprev[5] + acc[5]);
            h1.z += coef * (xprev[6] + acc[6]);
            h1.w += coef * (xprev[7] + acc[7]);
            *(float4*)hp = h0;
            *(float4*)(hp + 4) = h1;
        }
    }
}

// fused 3-layer MLP: out = relu(relu(h Wc^T+bc) W1^T+b1) W2^T+b2
__global__ __launch_bounds__(256) void mlp_kernel(const float* __restrict__ h,
                                                  const float* __restrict__ wc,
                                                  const float* __restrict__ bc,
                                                  const float* __restrict__ w1,
                                                  const float* __restrict__ b1,
                                                  const float* __restrict__ w2,
                                                  const float* __restrict__ b2,
                                                  float* __restrict__ out, int n) {
    __shared__ float ws[3][64 * 65];
    __shared__ float buf[32 * 64];
    int t = threadIdx.x;

    const float* wmats[3] = {wc, w1, w2};
    #pragma unroll
    for (int m = 0; m < 3; ++m) {
        const float* w = wmats[m];
        #pragma unroll
        for (int k = 0; k < 16; ++k) {
            int idx = t + k * 256;
            int j = idx >> 6, d = idx & 63;
            ws[m][d * 65 + j] = w[idx];
        }
    }

    int row0 = blockIdx.x * 32;
    const float4* in4 = (const float4*)h;
    #pragma unroll
    for (int k = 0; k < 2; ++k) {
        int idx = t + k * 256;
        int r = idx >> 4;
        int gr = row0 + r;
        float4 v = (gr < n) ? in4[(size_t)gr * 16 + (idx & 15)]
                            : make_float4(0.f, 0.f, 0.f, 0.f);
        ((float4*)buf)[idx] = v;
    }
    __syncthreads();

    int col = t & 63;
    int rg = t >> 6;
    const float* biases[3] = {bc, b1, b2};
    float so[8];
    #pragma unroll
    for (int m = 0; m < 3; ++m) {
        float acc[8] = {0.f, 0.f, 0.f, 0.f, 0.f, 0.f, 0.f, 0.f};
        #pragma unroll
        for (int d4 = 0; d4 < 16; ++d4) {
            int d = d4 * 4;
            float w0 = ws[m][(d + 0) * 65 + col];
            float w1v = ws[m][(d + 1) * 65 + col];
            float w2v = ws[m][(d + 2) * 65 + col];
            float w3v = ws[m][(d + 3) * 65 + col];
            #pragma unroll
            for (int r = 0; r < 8; ++r) {
                float4 bv = *(const float4*)&buf[(rg * 8 + r) * 64 + d];
                acc[r] += bv.x * w0 + bv.y * w1v + bv.z * w2v + bv.w * w3v;
            }
        }
        float bv = biases[m][col];
        #pragma unroll
        for (int r = 0; r < 8; ++r) {
            float v = acc[r] + bv;
            so[r] = (m < 2) ? fmaxf(v, 0.0f) : v;
        }
        __syncthreads();
        if (m < 2) {
            #pragma unroll
            for (int r = 0; r < 8; ++r) buf[(rg * 8 + r) * 64 + col] = so[r];
            __syncthreads();
        }
    }
    #pragma unroll
    for (int r = 0; r < 8; ++r) {
        int gr = row0 + rg * 8 + r;
        if (gr < n) out[(size_t)gr * 64 + col] = so[r];
    }
}

extern "C" void kernel_launch(void* const* d_in, const int* in_sizes, int n_in,
                              void* d_out, int out_size, void* d_ws, size_t ws_size,
                              hipStream_t stream) {
    const float* x      = (const float*)d_in[0];
    const float* w_conv = (const float*)d_in[1];
    const float* b_conv = (const float*)d_in[2];
    const float* w1     = (const float*)d_in[3];
    const float* b1     = (const float*)d_in[4];
    const float* w2     = (const float*)d_in[5];
    const float* b2     = (const float*)d_in[6];
    const int*   ei     = (const int*)d_in[7];

    int n = in_sizes[0] / DD;       // 50000
    int e = in_sizes[7] / 2;        // 800000
    const int* src = ei;
    const int* dst = ei + e;

    // workspace layout
    char* wsb = (char*)d_ws;
    const size_t SLOT = 256 * 1024;
    int*   cnt      = (int*)(wsb + 0 * SLOT);
    float* dinv     = (float*)(wsb + 1 * SLOT);
    int*   rowptr   = (int*)(wsb + 2 * SLOT);
    int*   cursor   = (int*)(wsb + 3 * SLOT);
    int*   partials = (int*)(wsb + 4 * SLOT);
    int2*  ecsr     = (int2*)(wsb + 5 * SLOT);                    // e*8 = 6.4 MB
    unsigned short* xb0 = (unsigned short*)(wsb + 5 * SLOT + (size_t)e * 8);
    unsigned short* xb1 = xb0 + (size_t)n * DD;                   // 6.4 MB each
    float* h = (float*)d_out;

    const int B = 256;
    int n4 = n * (DD / 4);
    int nb = (n + 255) / 256;

    hipMemsetAsync(cnt, 0, (size_t)n * sizeof(int), stream);
    deg_count_kernel<<<(e + B - 1) / B, B, 0, stream>>>(dst, cnt, e);
    dinv_kernel<<<(n + B - 1) / B, B, 0, stream>>>(cnt, dinv, n);
    scan1_kernel<<<nb, B, 0, stream>>>(cnt, partials, n);
    scan2_kernel<<<1, 1024, 0, stream>>>(partials, nb);
    scan3_kernel<<<nb, B, 0, stream>>>(cnt, partials, rowptr, cursor, n);
    fill_kernel<<<(e + B - 1) / B, B, 0, stream>>>(src, dst, dinv, cursor, ecsr, e);

    init_kernel<<<(n4 + B - 1) / B, B, 0, stream>>>(
        (const float4*)x, (float4*)h, (ushort4*)xb0, n4);

    float coef = (1.0f - ALPHA) / (float)KHOPS;
    int hblocks = (int)(((size_t)n * 64 + B - 1) / B);

    unsigned short* cur = xb0;
    unsigned short* nxt = xb1;
    for (int k = 1; k <= KHOPS; ++k) {
        if (k % 2 == 0)
            hop_kernel<1><<<hblocks, B, 0, stream>>>(rowptr, ecsr, dinv, cur, nxt, h,
                                                     coef, n);
        else
            hop_kernel<0><<<hblocks, B, 0, stream>>>(rowptr, ecsr, dinv, cur, nxt, h,
                                                     coef, n);
        unsigned short* tmp = cur; cur = nxt; nxt = tmp;
    }

    mlp_kernel<<<(n + 31) / 32, B, 0, stream>>>(h, w_conv, b_conv, w1, b1, w2, b2,
                                                (float*)d_out, n);
}

// Round 5
// 292.613 us; speedup vs baseline: 19.1160x; 1.3731x over previous
//
#include <hip/hip_runtime.h>

#define DD 64
#define ALPHA 0.6f
#define KHOPS 8
#define WP 72   // LDS row stride in bf16 elems (144 B = 9*16B: aligned, 2-way banks)

typedef __attribute__((ext_vector_type(8))) short bf16x8;
typedef __attribute__((ext_vector_type(4))) float f32x4;

static __device__ __forceinline__ unsigned short f2bf(float f) {
    unsigned int u = __float_as_uint(f);
    unsigned int r = (u + 0x7FFFu + ((u >> 16) & 1u)) >> 16;   // RTN-even
    return (unsigned short)r;
}
static __device__ __forceinline__ float bf2f(unsigned short h) {
    return __uint_as_float(((unsigned int)h) << 16);
}
static __device__ __forceinline__ unsigned int pack2bf(float lo, float hi) {
    return (unsigned int)f2bf(lo) | ((unsigned int)f2bf(hi) << 16);
}

__global__ __launch_bounds__(256) void deg_count_kernel(const int* __restrict__ dst,
                                                        int* __restrict__ cnt, int e) {
    int i = blockIdx.x * blockDim.x + threadIdx.x;
    if (i < e) atomicAdd(&cnt[dst[i]], 1);
}

__global__ __launch_bounds__(256) void dinv_kernel(const int* __restrict__ cnt,
                                                   float* __restrict__ dinv, int n) {
    int i = blockIdx.x * blockDim.x + threadIdx.x;
    if (i < n) dinv[i] = rsqrtf((float)(cnt[i] + 1));
}

// ---- hierarchical exclusive scan of cnt -> rowptr, cursor ----
__global__ __launch_bounds__(256) void scan1_kernel(const int* __restrict__ cnt,
                                                    int* __restrict__ partials, int n) {
    int i = blockIdx.x * 256 + threadIdx.x;
    int v = (i < n) ? cnt[i] : 0;
    #pragma unroll
    for (int off = 1; off < 64; off <<= 1) v += __shfl_down(v, off, 64);
    __shared__ int ws[4];
    if ((threadIdx.x & 63) == 0) ws[threadIdx.x >> 6] = v;
    __syncthreads();
    if (threadIdx.x == 0) partials[blockIdx.x] = ws[0] + ws[1] + ws[2] + ws[3];
}

__global__ __launch_bounds__(1024) void scan2_kernel(int* __restrict__ partials, int nb) {
    __shared__ int s[1024];
    int t = threadIdx.x;
    int v = (t < nb) ? partials[t] : 0;
    s[t] = v;
    __syncthreads();
    for (int off = 1; off < 1024; off <<= 1) {
        int tmp = (t >= off) ? s[t - off] : 0;
        __syncthreads();
        s[t] += tmp;
        __syncthreads();
    }
    if (t < nb) partials[t] = s[t] - v;   // exclusive
}

__global__ __launch_bounds__(256) void scan3_kernel(const int* __restrict__ cnt,
                                                    const int* __restrict__ partials,
                                                    int* __restrict__ rowptr,
                                                    int* __restrict__ cursor, int n) {
    int t = threadIdx.x;
    int i = blockIdx.x * 256 + t;
    int v = (i < n) ? cnt[i] : 0;
    int lane = t & 63;
    int incl = v;
    #pragma unroll
    for (int off = 1; off < 64; off <<= 1) {
        int u = __shfl_up(incl, off, 64);
        if (lane >= off) incl += u;
    }
    __shared__ int wsum[4];
    if (lane == 63) wsum[t >> 6] = incl;
    __syncthreads();
    int woff = 0;
    for (int w = 0; w < (t >> 6); ++w) woff += wsum[w];
    int excl = incl - v + woff + partials[blockIdx.x];
    if (i < n) { rowptr[i] = excl; cursor[i] = excl; }
    if (i == n - 1) rowptr[n] = excl + v;
}

__global__ __launch_bounds__(256) void fill_kernel(const int* __restrict__ src,
                                                   const int* __restrict__ dst,
                                                   const float* __restrict__ dinv,
                                                   int* __restrict__ cursor,
                                                   int2* __restrict__ ecsr, int e) {
    int i = blockIdx.x * blockDim.x + threadIdx.x;
    if (i >= e) return;
    int s = src[i], d = dst[i];
    int pos = atomicAdd(&cursor[d], 1);
    float w = dinv[s] * dinv[d];
    ecsr[pos] = make_int2(s, __float_as_int(w));
}

// h = ALPHA*x (f32) ; xb = bf16(x)
__global__ __launch_bounds__(256) void init_kernel(const float4* __restrict__ x,
                                                   float4* __restrict__ h,
                                                   ushort4* __restrict__ xb, int n4) {
    int i = blockIdx.x * blockDim.x + threadIdx.x;
    if (i >= n4) return;
    float4 v = x[i];
    h[i] = make_float4(ALPHA * v.x, ALPHA * v.y, ALPHA * v.z, ALPHA * v.w);
    ushort4 b;
    b.x = f2bf(v.x); b.y = f2bf(v.y); b.z = f2bf(v.z); b.w = f2bf(v.w);
    xb[i] = b;
}

static __device__ __forceinline__ void fma8(float* acc, uint4 v, float w) {
    acc[0] += w * __uint_as_float(v.x << 16);
    acc[1] += w * __uint_as_float(v.x & 0xffff0000u);
    acc[2] += w * __uint_as_float(v.y << 16);
    acc[3] += w * __uint_as_float(v.y & 0xffff0000u);
    acc[4] += w * __uint_as_float(v.z << 16);
    acc[5] += w * __uint_as_float(v.z & 0xffff0000u);
    acc[6] += w * __uint_as_float(v.w << 16);
    acc[7] += w * __uint_as_float(v.w & 0xffff0000u);
}

// One wave per node. lane = (group g = lane>>3) x (slice s = lane&7).
// 2x-unrolled octet loop: 4 VMEM in flight per wave (2 ecsr + 2 gathers).
template <int DO_H>
__global__ __launch_bounds__(256) void hop_kernel(const int* __restrict__ rowptr,
                                                  const int2* __restrict__ ecsr,
                                                  const float* __restrict__ dinv,
                                                  const unsigned short* __restrict__ xin,
                                                  unsigned short* __restrict__ xout,
                                                  float* __restrict__ h,
                                                  float coef, int n) {
    int wid = (blockIdx.x * blockDim.x + threadIdx.x) >> 6;   // wave id = node
    if (wid >= n) return;
    int lane = threadIdx.x & 63;
    int g = lane >> 3;
    int s = lane & 7;
    int node = wid;

    int e0 = rowptr[node];
    int e1 = rowptr[node + 1];

    float acc[8] = {0.f, 0.f, 0.f, 0.f, 0.f, 0.f, 0.f, 0.f};
    float xprev[8];

    if (g == 0) {
        float di = dinv[node];
        float w = di * di;
        uint4 v = *(const uint4*)(xin + (size_t)node * 64 + s * 8);
        xprev[0] = __uint_as_float(v.x << 16);
        xprev[1] = __uint_as_float(v.x & 0xffff0000u);
        xprev[2] = __uint_as_float(v.y << 16);
        xprev[3] = __uint_as_float(v.y & 0xffff0000u);
        xprev[4] = __uint_as_float(v.z << 16);
        xprev[5] = __uint_as_float(v.z & 0xffff0000u);
        xprev[6] = __uint_as_float(v.w << 16);
        xprev[7] = __uint_as_float(v.w & 0xffff0000u);
        #pragma unroll
        for (int j = 0; j < 8; ++j) acc[j] = w * xprev[j];
    }

    int deg = e1 - e0;
    int niter = (deg + 7) >> 3;
    int i = 0;
    for (; i + 1 < niter; i += 2) {
        int eA = e0 + (i << 3) + g;      // octet i is provably full
        int eB = eA + 8;                  // octet i+1 may be partial
        int2 edA = ecsr[eA];
        bool vB = eB < e1;
        int2 edB = ecsr[vB ? eB : (e1 - 1)];
        uint4 va = *(const uint4*)(xin + (size_t)edA.x * 64 + s * 8);
        uint4 vb = *(const uint4*)(xin + (size_t)edB.x * 64 + s * 8);
        fma8(acc, va, __int_as_float(edA.y));
        fma8(acc, vb, vB ? __int_as_float(edB.y) : 0.0f);
    }
    if (i < niter) {
        int eA = e0 + (i << 3) + g;
        bool vA = eA < e1;
        int2 edA = ecsr[vA ? eA : (e1 - 1)];
        uint4 va = *(const uint4*)(xin + (size_t)edA.x * 64 + s * 8);
        fma8(acc, va, vA ? __int_as_float(edA.y) : 0.0f);
    }

    #pragma unroll
    for (int off = 8; off < 64; off <<= 1) {
        #pragma unroll
        for (int j = 0; j < 8; ++j) acc[j] += __shfl_xor(acc[j], off, 64);
    }

    if (g == 0) {
        uint4 o;
        o.x = pack2bf(acc[0], acc[1]);
        o.y = pack2bf(acc[2], acc[3]);
        o.z = pack2bf(acc[4], acc[5]);
        o.w = pack2bf(acc[6], acc[7]);
        *(uint4*)(xout + (size_t)node * 64 + s * 8) = o;
        if (DO_H) {
            float* hp = h + (size_t)node * 64 + s * 8;
            float4 h0 = *(float4*)hp;
            float4 h1 = *(float4*)(hp + 4);
            h0.x += coef * (xprev[0] + acc[0]);
            h0.y += coef * (xprev[1] + acc[1]);
            h0.z += coef * (xprev[2] + acc[2]);
            h0.w += coef * (xprev[3] + acc[3]);
            h1.x += coef * (xprev[4] + acc[4]);
            h1.y += coef * (xprev[5] + acc[5]);
            h1.z += coef * (xprev[6] + acc[6]);
            h1.w += coef * (xprev[7] + acc[7]);
            *(float4*)hp = h0;
            *(float4*)(hp + 4) = h1;
        }
    }
}

// MFMA fused MLP: out = relu(relu(h Wc^T+bc) W1^T+b1) W2^T+b2
// Block = 256 thr = 4 waves; block covers 64 rows; wave owns 16 rows.
// A: row=lane&15, k=(lane>>4)*8+j ; B[k][c]=W[c][k] (8 contiguous bf16 of W row c)
// C/D: col=lane&15, row=(lane>>4)*4+reg  (m89-verified)
__global__ __launch_bounds__(256) void mlp_mfma_kernel(const float* __restrict__ hin,
                                                       const float* __restrict__ wc,
                                                       const float* __restrict__ bc,
                                                       const float* __restrict__ w1,
                                                       const float* __restrict__ b1,
                                                       const float* __restrict__ w2,
                                                       const float* __restrict__ b2,
                                                       float* __restrict__ out, int n) {
    __shared__ unsigned short wlds[3][64][WP];
    __shared__ unsigned short xlds[64][WP];
    int t = threadIdx.x;

    const float* wm[3] = {wc, w1, w2};
    #pragma unroll
    for (int m = 0; m < 3; ++m) {
        const float4* w4 = (const float4*)wm[m];
        #pragma unroll
        for (int k = 0; k < 4; ++k) {
            int fid = t + k * 256;               // 0..1023 float4s
            int j = fid >> 4, c4 = fid & 15;
            float4 v = w4[fid];
            *(uint2*)&wlds[m][j][c4 * 4] =
                make_uint2(pack2bf(v.x, v.y), pack2bf(v.z, v.w));
        }
    }

    int r0 = blockIdx.x * 64;
    const float4* h4 = (const float4*)hin;
    #pragma unroll
    for (int k = 0; k < 4; ++k) {
        int fid = t + k * 256;
        int r = fid >> 4, c4 = fid & 15;
        int gr = r0 + r;
        float4 v = (gr < n) ? h4[(size_t)gr * 16 + c4]
                            : make_float4(0.f, 0.f, 0.f, 0.f);
        *(uint2*)&xlds[r][c4 * 4] = make_uint2(pack2bf(v.x, v.y), pack2bf(v.z, v.w));
    }
    __syncthreads();

    int lane = t & 63;
    int wv = t >> 6;
    int rbase = wv * 16;
    int lr = lane & 15;
    int kg = lane >> 4;
    const float* bias[3] = {bc, b1, b2};

    #pragma unroll
    for (int m = 0; m < 3; ++m) {
        bf16x8 a0 = *(bf16x8*)&xlds[rbase + lr][kg * 8];
        bf16x8 a1 = *(bf16x8*)&xlds[rbase + lr][32 + kg * 8];
        #pragma unroll
        for (int ct = 0; ct < 4; ++ct) {
            bf16x8 bv0 = *(bf16x8*)&wlds[m][ct * 16 + lr][kg * 8];
            bf16x8 bv1 = *(bf16x8*)&wlds[m][ct * 16 + lr][32 + kg * 8];
            f32x4 acc = {0.f, 0.f, 0.f, 0.f};
            acc = __builtin_amdgcn_mfma_f32_16x16x32_bf16(a0, bv0, acc, 0, 0, 0);
            acc = __builtin_amdgcn_mfma_f32_16x16x32_bf16(a1, bv1, acc, 0, 0, 0);
            float bb = bias[m][ct * 16 + lr];
            if (m < 2) {
                #pragma unroll
                for (int rg = 0; rg < 4; ++rg) {
                    float v = fmaxf(acc[rg] + bb, 0.0f);
                    xlds[rbase + kg * 4 + rg][ct * 16 + lr] = f2bf(v);
                }
            } else {
                #pragma unroll
                for (int rg = 0; rg < 4; ++rg) {
                    int gr = r0 + rbase + kg * 4 + rg;
                    if (gr < n) out[(size_t)gr * 64 + ct * 16 + lr] = acc[rg] + bb;
                }
            }
        }
        // wave reads only its own 16 rows next layer: program order suffices
    }
}

extern "C" void kernel_launch(void* const* d_in, const int* in_sizes, int n_in,
                              void* d_out, int out_size, void* d_ws, size_t ws_size,
                              hipStream_t stream) {
    const float* x      = (const float*)d_in[0];
    const float* w_conv = (const float*)d_in[1];
    const float* b_conv = (const float*)d_in[2];
    const float* w1     = (const float*)d_in[3];
    const float* b1     = (const float*)d_in[4];
    const float* w2     = (const float*)d_in[5];
    const float* b2     = (const float*)d_in[6];
    const int*   ei     = (const int*)d_in[7];

    int n = in_sizes[0] / DD;       // 50000
    int e = in_sizes[7] / 2;        // 800000
    const int* src = ei;
    const int* dst = ei + e;

    char* wsb = (char*)d_ws;
    const size_t SLOT = 256 * 1024;
    int*   cnt      = (int*)(wsb + 0 * SLOT);
    float* dinv     = (float*)(wsb + 1 * SLOT);
    int*   rowptr   = (int*)(wsb + 2 * SLOT);
    int*   cursor   = (int*)(wsb + 3 * SLOT);
    int*   partials = (int*)(wsb + 4 * SLOT);
    int2*  ecsr     = (int2*)(wsb + 5 * SLOT);                    // e*8 = 6.4 MB
    unsigned short* xb0 = (unsigned short*)(wsb + 5 * SLOT + (size_t)e * 8);
    unsigned short* xb1 = xb0 + (size_t)n * DD;                   // 6.4 MB each
    float* h = (float*)d_out;

    const int B = 256;
    int n4 = n * (DD / 4);
    int nb = (n + 255) / 256;

    hipMemsetAsync(cnt, 0, (size_t)n * sizeof(int), stream);
    deg_count_kernel<<<(e + B - 1) / B, B, 0, stream>>>(dst, cnt, e);
    dinv_kernel<<<(n + B - 1) / B, B, 0, stream>>>(cnt, dinv, n);
    scan1_kernel<<<nb, B, 0, stream>>>(cnt, partials, n);
    scan2_kernel<<<1, 1024, 0, stream>>>(partials, nb);
    scan3_kernel<<<nb, B, 0, stream>>>(cnt, partials, rowptr, cursor, n);
    fill_kernel<<<(e + B - 1) / B, B, 0, stream>>>(src, dst, dinv, cursor, ecsr, e);

    init_kernel<<<(n4 + B - 1) / B, B, 0, stream>>>(
        (const float4*)x, (float4*)h, (ushort4*)xb0, n4);

    float coef = (1.0f - ALPHA) / (float)KHOPS;
    int hblocks = (int)(((size_t)n * 64 + B - 1) / B);

    unsigned short* cur = xb0;
    unsigned short* nxt = xb1;
    for (int k = 1; k <= KHOPS; ++k) {
        if (k % 2 == 0)
            hop_kernel<1><<<hblocks, B, 0, stream>>>(rowptr, ecsr, dinv, cur, nxt, h,
                                                     coef, n);
        else
            hop_kernel<0><<<hblocks, B, 0, stream>>>(rowptr, ecsr, dinv, cur, nxt, h,
                                                     coef, n);
        unsigned short* tmp = cur; cur = nxt; nxt = tmp;
    }

    mlp_mfma_kernel<<<(n + 63) / 64, B, 0, stream>>>(h, w_conv, b_conv, w1, b1,
                                                     w2, b2, (float*)d_out, n);
}